// Round 13
// baseline (311.551 us; speedup 1.0000x reference)
//
#include <hip/hip_runtime.h>
#include <math.h>

#define NB 4096
#define NR 49
#define NS 50
#define ND 512
#define NK 100
#define NT 7            // n-tiles of 16 cols (112 >= 100)
#define KSTEPS 16       // 512 / 32
#define FRAGS (NT * KSTEPS * 64 * 8)   // 57344 ushorts (114688 B) per weight matrix

typedef __attribute__((ext_vector_type(8))) short short8;
typedef __attribute__((ext_vector_type(4))) float f32x4;

__device__ __forceinline__ unsigned short f32_bf16(float f) {
    union { float f; unsigned u; } x; x.f = f;
    return (unsigned short)((x.u + 0x7fffu + ((x.u >> 16) & 1u)) >> 16);  // RNE
}
__device__ __forceinline__ unsigned cvt_pk_bf16(float lo, float hi) {
    unsigned r;
    asm("v_cvt_pk_bf16_f32 %0, %1, %2" : "=v"(r) : "v"(lo), "v"(hi));
    return r;
}
__device__ __forceinline__ float fast_tanh(float x) {
    const float ax = fabsf(x);
    const float e = __expf(2.f * ax);            // inf for large ax -> r = 1
    const float r = 1.f - 2.f / (e + 1.f);
    return copysignf(r, x);
}
// async global->LDS DMA, 16B/lane, zero VGPR cost; LDS dest is wave-uniform
// base + lane*16 (linear), swizzle lives in the per-lane global address.
__device__ __forceinline__ void load_lds16(const float* g, float* l) {
    __builtin_amdgcn_global_load_lds(
        (const __attribute__((address_space(1))) unsigned int*)(const void*)g,
        (__attribute__((address_space(3))) unsigned int*)(void*)l, 16, 0, 0);
}
#define FENCE() asm volatile("" ::: "memory")
#define BARR()  do { FENCE(); __builtin_amdgcn_s_barrier(); FENCE(); } while (0)
#define WAITV(N) asm volatile("s_waitcnt vmcnt(" #N ")" ::: "memory")

// ---------------------------------------------------------------------------
// Pre-pass: 2 weight matrices [512][100] f32 -> bf16 MFMA B-fragments.
// (Only w_Vi_0 / w_Vt_1 needed: broadcast conditioning branches cancel in
//  softmax; the two attention passes are fully independent.)
// frag(t, gk): lane l holds W[k = gk*32 + (l>>4)*8 + j][col = t*16 + (l&15)].
// ---------------------------------------------------------------------------
__global__ void preswz_kernel(const float* __restrict__ w0, const float* __restrict__ w1,
                              unsigned short* __restrict__ ws)
{
    const int l  = threadIdx.x;          // 64
    const int gk = blockIdx.x & 15;
    const int t  = blockIdx.x >> 4;      // 0..6
    const int m  = blockIdx.y;           // 0..1
    const float* W = m ? w1 : w0;
    const int col = t * 16 + (l & 15);
    const int k0  = gk * 32 + (l >> 4) * 8;
    unsigned short* o = ws + (size_t)m * FRAGS + ((size_t)(t * 16 + gk) * 64 + l) * 8;
#pragma unroll
    for (int j = 0; j < 8; ++j) {
        float v = (col < NK) ? W[(size_t)(k0 + j) * NK + col] : 0.f;
        o[j] = f32_bf16(v);
    }
}

// ---------------------------------------------------------------------------
// Main kernel: one block per (batch, pass), 512 threads (8 waves).
// Features stream HBM -> LDS as f32 via async global_load_lds (4 chunks of
// [50][128] f32 through 2 buffers, counted vmcnt + raw barriers). GEMM
// converts f32->bf16 at fragment build. Weighted sum fully unrolled
// (compile-time 49/50) so all row loads pipeline ahead of the fadd chain.
// atomicAdd combine (out pre-zeroed; 2 commutative adds = deterministic).
// ---------------------------------------------------------------------------
struct SM {
    float bufA[50 * 128];    // 25600 B f32 chunk (linear rows of 512 B)
    float bufB[50 * 128];
    float part[8][64];       // per-wave row partials (rows mh*32..+32 valid)
    float P[64];
};

__global__ __launch_bounds__(512, 4) void coattn_main(
    const float* __restrict__ ifeat, const float* __restrict__ tfeat,
    const float* __restrict__ wPi0, const float* __restrict__ bPi0,
    const float* __restrict__ wPi1, const float* __restrict__ bPi1,
    const unsigned short* __restrict__ wsW, float* __restrict__ out)
{
    __shared__ SM sm;
    const int pass = blockIdx.x & 1;
    const int b    = blockIdx.x >> 1;
    const int tid  = threadIdx.x;

    const float* feat = pass ? (tfeat + (size_t)b * NS * ND) : (ifeat + (size_t)b * NR * ND);
    const int nrows  = pass ? NS : NR;
    const int nclamp = nrows - 1;
    const unsigned short* wsR = wsW + (size_t)pass * FRAGS;
    const float* wPiRow = pass ? (wPi1 + NK) : wPi0;
    const float* bvec   = pass ? bPi1 : bPi0;

    const int lane = tid & 63, wid = tid >> 6;
    const int colg = lane & 15, g = lane >> 4;
    const int q  = wid >> 1;          // tile-pair 0..3
    const int mh = wid & 1;           // row-half
    const int t0 = q * 2;
    const int two = (q < 3);          // q==3 owns only tile 6

    int arow_[2], aswz_[2];
#pragma unroll
    for (int rl = 0; rl < 2; ++rl) {
        const int r0 = (mh * 2 + rl) * 16 + colg;
        arow_[rl] = (r0 < nclamp) ? r0 : nclamp;
        aswz_[rl] = arow_[rl] & 7;
    }
    const unsigned short* wl0 = wsR + ((size_t)t0 * 16 * 64 + lane) * 8;
    const unsigned short* wl1 = wl0 + (size_t)16 * 64 * 8;

    // -- staging: instr j (0..24) covers LDS rows 2j,2j+1; lane: row = 2j+(l>>5),
    //    c16 = l&31; global source pre-XOR-swizzled so readers can de-swizzle.
#define ISSUE(CP, BUF)                                                          \
    do {                                                                        \
        _Pragma("unroll") for (int s = 0; s < 3; ++s) {                         \
            const int j = wid + (s << 3);                                       \
            const int row = 2 * j + (lane >> 5);                                \
            const int grow = (row < nrows) ? row : nclamp;                      \
            const int c16 = lane & 31;                                          \
            load_lds16(feat + (grow << 9) + ((CP) << 7) + ((c16 ^ (row & 7)) << 2), \
                       sm.BUF + j * 256);                                       \
        }                                                                       \
        if (wid == 0) {                                                         \
            const int row = 48 + (lane >> 5);                                   \
            const int grow = (row < nrows) ? row : nclamp;                      \
            const int c16 = lane & 31;                                          \
            load_lds16(feat + (grow << 9) + ((CP) << 7) + ((c16 ^ (row & 7)) << 2), \
                       sm.BUF + 24 * 256);                                      \
        }                                                                       \
    } while (0)
#define WAITC() do { if (wid == 0) { WAITV(4); } else { WAITV(3); } } while (0)

    f32x4 acc[2][2];
#pragma unroll
    for (int rl = 0; rl < 2; ++rl)
#pragma unroll
        for (int tl = 0; tl < 2; ++tl) acc[rl][tl] = f32x4{0.f, 0.f, 0.f, 0.f};

#define GEMMP(LB, CP)                                                           \
    do {                                                                        \
        _Pragma("unroll") for (int ksl = 0; ksl < 4; ++ksl) {                   \
            const int ks = (CP) * 4 + ksl;                                      \
            const short8 wf0 = *reinterpret_cast<const short8*>(wl0 + ks * 512); \
            short8 wf1 = {};                                                    \
            if (two) wf1 = *reinterpret_cast<const short8*>(wl1 + ks * 512);    \
            _Pragma("unroll") for (int rl = 0; rl < 2; ++rl) {                  \
                const int c16 = (ksl << 3) + (g << 1);                          \
                const float4 fa = *reinterpret_cast<const float4*>(             \
                    &(LB)[arow_[rl] * 128 + ((c16 ^ aswz_[rl]) << 2)]);         \
                const float4 fb = *reinterpret_cast<const float4*>(             \
                    &(LB)[arow_[rl] * 128 + (((c16 + 1) ^ aswz_[rl]) << 2)]);   \
                uint4 ap;                                                       \
                ap.x = cvt_pk_bf16(fa.x, fa.y); ap.y = cvt_pk_bf16(fa.z, fa.w); \
                ap.z = cvt_pk_bf16(fb.x, fb.y); ap.w = cvt_pk_bf16(fb.z, fb.w); \
                const short8 a = *reinterpret_cast<const short8*>(&ap);         \
                acc[rl][0] = __builtin_amdgcn_mfma_f32_16x16x32_bf16(a, wf0, acc[rl][0], 0, 0, 0); \
                if (two)                                                        \
                    acc[rl][1] = __builtin_amdgcn_mfma_f32_16x16x32_bf16(a, wf1, acc[rl][1], 0, 0, 0); \
            }                                                                   \
        }                                                                       \
    } while (0)

    // ---- pipelined stream: 4 chunks, 2 buffers, counted vmcnt
    ISSUE(0, bufA);
    ISSUE(1, bufB);
    WAITC(); BARR();          // chunk0 in LDS (chunk1 still in flight)
    GEMMP(sm.bufA, 0);
    BARR();                   // all waves done reading bufA
    ISSUE(2, bufA);
    WAITC(); BARR();          // chunk1 in LDS (chunk2 in flight)
    GEMMP(sm.bufB, 1);
    BARR();
    ISSUE(3, bufB);
    WAITC(); BARR();          // chunk2 in LDS (chunk3 in flight)
    GEMMP(sm.bufA, 2);
    WAITV(0); BARR();         // chunk3 in LDS
    GEMMP(sm.bufB, 3);

    // ---- epilogue: per-wave row partials (sum over this wave's 1-2 tiles)
    {
        const int c0 = (t0 + 0) * 16 + colg;
        const int c1 = (t0 + 1) * 16 + colg;
        const float w0 = (c0 < NK) ? wPiRow[c0] : 0.f;
        const float w1 = (two && c1 < NK) ? wPiRow[c1] : 0.f;
        float sp[2][4];
#pragma unroll
        for (int rl = 0; rl < 2; ++rl)
#pragma unroll
            for (int i = 0; i < 4; ++i) {
                float v = fast_tanh(acc[rl][0][i]) * w0;
                if (two) v += fast_tanh(acc[rl][1][i]) * w1;
                sp[rl][i] = v;
            }
#pragma unroll
        for (int off = 1; off < 16; off <<= 1)
#pragma unroll
            for (int rl = 0; rl < 2; ++rl)
#pragma unroll
                for (int i = 0; i < 4; ++i)
                    sp[rl][i] += __shfl_xor(sp[rl][i], off);
        if (colg == 0) {
#pragma unroll
            for (int rl = 0; rl < 2; ++rl)
#pragma unroll
                for (int i = 0; i < 4; ++i)
                    sm.part[wid][(mh * 2 + rl) * 16 + g * 4 + i] = sp[rl][i];
        }
    }
    __syncthreads();

    if (tid < 64) {   // softmax over rows; row r lives in waves {2q + (r>=32)}
        const int hb = (tid >= 32) ? 1 : 0;
        float v = (tid < nrows) ? bvec[tid] : 0.f;
#pragma unroll
        for (int qq = 0; qq < 4; ++qq) v += sm.part[2 * qq + hb][tid];
        v = (tid < nrows) ? v : -3.0e38f;
        float mx = v;
#pragma unroll
        for (int off = 32; off; off >>= 1) mx = fmaxf(mx, __shfl_xor(mx, off));
        const float e = (tid < nrows) ? __expf(v - mx) : 0.f;
        float su = e;
#pragma unroll
        for (int off = 32; off; off >>= 1) su += __shfl_xor(su, off);
        sm.P[tid] = e / su;
    }
    __syncthreads();

    // ---- weighted sum, FULLY UNROLLED (compile-time trip count): all row
    //      loads issue ahead of the dependent fadd chain instead of one
    //      exposed L2 round trip per iteration.
    {
        float v = 0.f;
        const float* fp = feat + tid;
        if (pass == 0) {
#pragma unroll
            for (int r = 0; r < NR; ++r) v += sm.P[r] * fp[(size_t)r << 9];
        } else {
#pragma unroll
            for (int r = 0; r < NS; ++r) v += sm.P[r] * fp[(size_t)r << 9];
        }
        atomicAdd(&out[(size_t)b * ND + tid], v);
    }
#undef ISSUE
#undef WAITC
#undef GEMMP
}

extern "C" void kernel_launch(void* const* d_in, const int* in_sizes, int n_in,
                              void* d_out, int out_size, void* d_ws, size_t ws_size,
                              hipStream_t stream) {
    const float* ifeat = (const float*)d_in[0];
    const float* tfeat = (const float*)d_in[1];
    const float* wVi0  = (const float*)d_in[2];
    const float* wPi0  = (const float*)d_in[4];
    const float* bPi0  = (const float*)d_in[5];
    const float* wVt1  = (const float*)d_in[7];
    const float* wPi1  = (const float*)d_in[8];
    const float* bPi1  = (const float*)d_in[9];
    float* outp = (float*)d_out;
    unsigned short* wsW = (unsigned short*)d_ws;   // 2*114688 = 229376 B

    hipMemsetAsync(outp, 0, (size_t)NB * ND * sizeof(float), stream);
    hipLaunchKernelGGL(preswz_kernel, dim3(NT * KSTEPS, 2), dim3(64), 0, stream,
                       wVi0, wVt1, wsW);
    hipLaunchKernelGGL(coattn_main, dim3(2 * NB), dim3(512), 0, stream,
                       ifeat, tfeat, wPi0, bPi0, wPi1, bPi1, wsW, outp);
}